// Round 10
// baseline (682.889 us; speedup 1.0000x reference)
//
#include <hip/hip_runtime.h>
#include <math.h>

// TreeLSTM encoder v4: single persistent kernel, manual software grid barrier,
// counted-vmcnt pipelined K-loop (identical math to passing v3).
// ws layout (bytes):
//   [0,16M)    Hhi plane: [65536][128] bf16
//   [16M,32M)  Hlo plane: [65536][128] bf16
//   [32M,64M)  C plane:   [65536][128] f32
//   [64M,+640K) W_ext:    [640 cols][512] bf16 (k<256 hi, k>=256 lo)
//   [68M,+64B) barrier counters (16 x u32), zeroed by init kernel each call
// K_ext = 768: term0 Xh*Wh, term1 Xh*Wl, term2 Xl*Wh.

typedef __attribute__((ext_vector_type(8))) short s8_t;
typedef __attribute__((ext_vector_type(4))) float f32x4;

#define PLANE_DELTA 8388608   // ushorts between Hhi and Hlo planes
#define NB 512                // grid size; 2 blocks/CU x 256 CUs -> all co-resident

__device__ __forceinline__ float sigf(float x){ return 1.0f/(1.0f+expf(-x)); }

__device__ __forceinline__ unsigned short f2bf_rne(float x){
    unsigned int u = __builtin_bit_cast(unsigned int, x);
    unsigned int r = (u + 0x7FFFu + ((u>>16)&1u)) >> 16;
    return (unsigned short)r;
}
__device__ __forceinline__ float bf2f(unsigned short b){
    return __builtin_bit_cast(float, ((unsigned int)b)<<16);
}
__device__ __forceinline__ void gl_lds16(const void* g, void* l){
    __builtin_amdgcn_global_load_lds(
        (const __attribute__((address_space(1))) unsigned int*)g,
        (__attribute__((address_space(3))) unsigned int*)l, 16, 0, 0);
}

// software grid barrier: one dedicated counter per sync point (no reuse races).
// __syncthreads drains this wave-set's vmem (compiler emits vmcnt(0) before
// s_barrier), RELEASE add publishes to agent scope, RELAXED polls avoid
// cache-invalidate thrash, final threadfence = acquire for data reads.
__device__ __forceinline__ void gridbar(unsigned int* cnt) {
    __syncthreads();
    if (threadIdx.x == 0) {
        __hip_atomic_fetch_add(cnt, 1u, __ATOMIC_RELEASE, __HIP_MEMORY_SCOPE_AGENT);
        while (__hip_atomic_load(cnt, __ATOMIC_RELAXED, __HIP_MEMORY_SCOPE_AGENT) < (unsigned)NB)
            __builtin_amdgcn_s_sleep(8);
        __threadfence();
    }
    __syncthreads();
}

__global__ void init_bar(unsigned int* bar) {
    if (threadIdx.x < 16) bar[threadIdx.x] = 0;
}

__global__ __launch_bounds__(256, 2) void fused(
    const int* __restrict__ tokens, const int* __restrict__ left,
    const int* __restrict__ right, const float* __restrict__ emb,
    const float* __restrict__ Wu, const float* __restrict__ bu,
    const float* __restrict__ Wb, const float* __restrict__ bb,
    float* __restrict__ out, unsigned short* __restrict__ Hhi,
    float* __restrict__ C, unsigned short* __restrict__ Wext,
    unsigned int* __restrict__ bar)
{
    __shared__ __align__(16) unsigned short SL[4 * 9216];   // 72 KB: 4 bufs x (8KB A + 10KB B)
    __shared__ __align__(16) unsigned short dmy[1024];      // 2 KB dummy strip
    __shared__ int sLR[256];

    const int b = blockIdx.x, tid = threadIdx.x;
    const int lane = tid & 63, w = tid >> 6;
    const char* HhiB  = (const char*)Hhi;
    const char* WextB = (const char*)Wext;

    // ---------------- phase 0a: prep W_ext ----------------
    for (int idx = b * 256 + tid; idx < 640 * 256; idx += NB * 256) {
        int nn = idx >> 8, k = idx & 255;
        float x = Wb[k * 640 + nn];
        unsigned short h = f2bf_rne(x);
        Wext[nn * 512 + k]       = h;
        Wext[nn * 512 + 256 + k] = f2bf_rne(x - bf2f(h));
    }

    // ---------------- phase 0b: leaves (64 nodes/block, 16/wave) ----------------
    {
        int nbase = b * 64 + w * 16;
        for (int i = 0; i < 16; ++i) {
            int node = nbase + i;
            int tok = tokens[node];
            float2 e = *(const float2*)(emb + (size_t)tok * 128 + lane * 2);
            float ss = e.x * e.x + e.y * e.y;
#pragma unroll
            for (int off = 32; off; off >>= 1) ss += __shfl_xor(ss, off, 64);
            float nrm = sqrtf(ss);
            float scale = fminf(1.0f, 1.0f / fmaxf(nrm, 1e-7f));
            float hx = e.x * scale, hy = e.y * scale;
            unsigned short hxh = f2bf_rne(hx), hyh = f2bf_rne(hy);
            unsigned short hxl = f2bf_rne(hx - bf2f(hxh)), hyl = f2bf_rne(hy - bf2f(hyh));
            size_t p = (size_t)node * 128 + lane * 2;
            *(unsigned int*)(Hhi + p)               = (unsigned int)hxh | ((unsigned int)hyh << 16);
            *(unsigned int*)(Hhi + p + PLANE_DELTA) = (unsigned int)hxl | ((unsigned int)hyl << 16);
            *(float2*)(C + p) = make_float2(0.f, 0.f);
            int t = node >> 9, j = node & 511;
            *(float2*)(out + ((size_t)t * 1024 + j) * 128 + lane * 2) = make_float2(hx, hy);
        }
    }
    gridbar(&bar[0]);

    // ---------------- levels 1..9: binary combine ----------------
#pragma unroll 1
    for (int l = 1; l <= 9; ++l) {
        const int n_nodes = 32768 >> l;
        const int s       = 65536 - (65536 >> l);
        const int ooff    = 1024 - (1024 >> l);
        const int lg      = 9 - l;
        const int Tx      = (n_nodes + 127) >> 7;
        const int active  = Tx * 4;

        if (b < active) {
            // XCD-friendly bijective tile swizzle (active is a multiple of 8 when >=8)
            int t = b;
            if (active >= 8) { int q = active >> 3; t = (b & 7) * q + (b >> 3); }
            const int bm0 = (t >> 2) * 128;
            const int d0  = (t & 3) * 32;

            if (tid < 128) {
                int r = bm0 + tid; if (r >= n_nodes) r = n_nodes - 1;
                sLR[tid]       = left[s + r];
                sLR[128 + tid] = right[s + r];
            }
            __syncthreads();

            int aOffL[2], aOffR[2];
#pragma unroll
            for (int j = 0; j < 2; ++j) {
                int ch = tid + j * 256, row = ch >> 2, slot = ch & 3;
                int g = slot ^ ((row >> 1) & 3);
                aOffL[j] = sLR[row] * 256 + g * 16;
                aOffR[j] = sLR[128 + row] * 256 + g * 16;
            }
            int bOff0, bOff1, bOff2;
            {
                int nn = tid >> 2, slot = tid & 3;
                int g = slot ^ ((nn >> 1) & 3);
                bOff0 = ((nn >> 5) * 128 + d0 + (nn & 31)) * 1024 + g * 16;
            }
            {
                int ch = tid + 256, nn = ch >> 2, slot = ch & 3;
                int g = slot ^ ((nn >> 1) & 3);
                bOff1 = ((nn >> 5) * 128 + d0 + (nn & 31)) * 1024 + g * 16;
            }
            if (tid < 128) {
                int ch = tid + 512, nn = ch >> 2, slot = ch & 3;
                int g = slot ^ ((nn >> 1) & 3);
                bOff2 = ((nn >> 5) * 128 + d0 + (nn & 31)) * 1024 + g * 16;
            } else {
                bOff2 = 0;
            }

            f32x4 acc[2][10];
#pragma unroll
            for (int i = 0; i < 2; ++i)
#pragma unroll
                for (int j = 0; j < 10; ++j) acc[i][j] = f32x4{0.f, 0.f, 0.f, 0.f};

            auto stage = [&](int st, int buf) {
                const int tm    = st >> 3;
                const int k256  = (st & 7) * 32;
                const int side  = k256 >> 7;
                const int aoffB = ((tm == 2) ? PLANE_DELTA * 2 : 0) + (k256 & 127) * 2;
                const int koffB = ((tm == 1) ? (256 + k256) : k256) * 2;
                char* Abase = (char*)SL + buf * 18432;
                char* Bbase = Abase + 8192;
                const int a0 = side ? aOffR[0] : aOffL[0];
                const int a1 = side ? aOffR[1] : aOffL[1];
                gl_lds16(HhiB + (size_t)(a0 + aoffB), Abase + w * 1024);
                gl_lds16(HhiB + (size_t)(a1 + aoffB), Abase + 4096 + w * 1024);
                gl_lds16(WextB + (size_t)(bOff0 + koffB), Bbase + w * 1024);
                gl_lds16(WextB + (size_t)(bOff1 + koffB), Bbase + 4096 + w * 1024);
                gl_lds16(WextB + (size_t)(bOff2 + koffB),
                         (w < 2) ? (void*)(Bbase + 8192 + w * 1024)
                                 : (void*)((char*)dmy + (w - 2) * 1024));
            };

            const int r15  = lane & 15;
            const int sl_  = (lane >> 4) ^ ((r15 >> 1) & 3);
            const int offA = w * 2048 + r15 * 64 + sl_ * 16;
            const int offB = r15 * 64 + sl_ * 16;

            stage(0, 0);
            stage(1, 1);
            stage(2, 2);
            int cbuf = 0, sbuf = 3;
#pragma unroll 1
            for (int st = 0; st < 24; ++st) {
                // oldest-first retire: any older epilogue stores drain before these counts
                if (st <= 21)      asm volatile("s_waitcnt vmcnt(10)" ::: "memory");
                else if (st == 22) asm volatile("s_waitcnt vmcnt(5)"  ::: "memory");
                else               asm volatile("s_waitcnt vmcnt(0)"  ::: "memory");
                __builtin_amdgcn_sched_barrier(0);
                __builtin_amdgcn_s_barrier();
                __builtin_amdgcn_sched_barrier(0);
                if (st + 3 < 24) stage(st + 3, sbuf);
                const char* Ap = (const char*)SL + cbuf * 18432;
                const char* Bp = Ap + 8192;
                s8_t a0v = *(const s8_t*)(Ap + offA);
                s8_t a1v = *(const s8_t*)(Ap + offA + 1024);
#pragma unroll
                for (int fn = 0; fn < 10; ++fn) {
                    s8_t bf = *(const s8_t*)(Bp + offB + fn * 1024);
                    acc[0][fn] = __builtin_amdgcn_mfma_f32_16x16x32_bf16(a0v, bf, acc[0][fn], 0, 0, 0);
                    acc[1][fn] = __builtin_amdgcn_mfma_f32_16x16x32_bf16(a1v, bf, acc[1][fn], 0, 0, 0);
                }
                cbuf = (cbuf == 3) ? 0 : cbuf + 1;
                sbuf = (sbuf == 3) ? 0 : sbuf + 1;
            }

            // -------- epilogue: fused LSTM gates --------
            float bias[5][2];
#pragma unroll
            for (int g = 0; g < 5; ++g) {
                bias[g][0] = bb[g * 128 + d0 + r15];
                bias[g][1] = bb[g * 128 + d0 + 16 + r15];
            }
#pragma unroll
            for (int fm = 0; fm < 2; ++fm) {
                const int rb = w * 32 + fm * 16 + ((lane >> 4) << 2);
#pragma unroll
                for (int reg = 0; reg < 4; ++reg) {
                    const int rl = rb + reg;
                    const int nl = bm0 + rl;
                    const bool valid = nl < n_nodes;
                    const int node = s + (valid ? nl : 0);
                    const int ln = sLR[rl], rn = sLR[128 + rl];
#pragma unroll
                    for (int hi = 0; hi < 2; ++hi) {
                        const int d = d0 + hi * 16 + r15;
                        float gi  = acc[fm][0 + hi][reg] + bias[0][hi];
                        float go  = acc[fm][2 + hi][reg] + bias[1][hi];
                        float gu  = acc[fm][4 + hi][reg] + bias[2][hi];
                        float gfl = acc[fm][6 + hi][reg] + bias[3][hi];
                        float gfr = acc[fm][8 + hi][reg] + bias[4][hi];
                        float lc = C[(size_t)ln * 128 + d];
                        float rc = C[(size_t)rn * 128 + d];
                        float c = sigf(gi) * tanhf(gu) + sigf(gfl) * lc + sigf(gfr) * rc;
                        float h = sigf(go) * tanhf(c);
                        if (valid) {
                            size_t p = (size_t)node * 128 + d;
                            unsigned short hh = f2bf_rne(h);
                            Hhi[p]               = hh;
                            Hhi[p + PLANE_DELTA] = f2bf_rne(h - bf2f(hh));
                            C[p] = c;
                            const int tt = nl >> lg, j = nl & ((1 << lg) - 1);
                            out[((size_t)tt * 1024 + ooff + j) * 128 + d] = h;
                        }
                    }
                }
            }
        }
        gridbar(&bar[l]);
    }

    // ---------------- level 10: unary head (blocks 0..3) ----------------
    if (b < 4) {
        float* X = (float*)SL;
        const int bm0 = b * 16;
        const int s10 = 65472;
        for (int i = tid; i < 16 * 128; i += 256) {
            int m = i >> 7, d = i & 127;
            int ch = left[s10 + bm0 + m];
            size_t p = (size_t)ch * 128 + d;
            X[m * 128 + d] = bf2f(Hhi[p]) + bf2f(Hhi[p + PLANE_DELTA]);
        }
        __syncthreads();

        float acc0[16], acc1[16];
#pragma unroll
        for (int m = 0; m < 16; ++m) { acc0[m] = 0.f; acc1[m] = 0.f; }

        for (int k4 = 0; k4 < 32; ++k4) {
            const int k = k4 * 4;
            float w0[4], w1[4];
#pragma unroll
            for (int r = 0; r < 4; ++r) {
                w0[r] = Wu[(k + r) * 512 + tid];
                w1[r] = Wu[(k + r) * 512 + tid + 256];
            }
#pragma unroll
            for (int m = 0; m < 16; ++m) {
                float4 xv = *(const float4*)(X + m * 128 + k);
                acc0[m] = fmaf(xv.x, w0[0], fmaf(xv.y, w0[1], fmaf(xv.z, w0[2], fmaf(xv.w, w0[3], acc0[m]))));
                acc1[m] = fmaf(xv.x, w1[0], fmaf(xv.y, w1[1], fmaf(xv.z, w1[2], fmaf(xv.w, w1[3], acc1[m]))));
            }
        }

        float b0 = bu[tid], b1 = bu[tid + 256];
        __syncthreads();
        float* Gm = (float*)SL;
#pragma unroll
        for (int m = 0; m < 16; ++m) {
            Gm[m * 512 + tid]       = acc0[m] + b0;
            Gm[m * 512 + tid + 256] = acc1[m] + b1;
        }
        __syncthreads();

        for (int i = tid; i < 16 * 128; i += 256) {
            int m = i >> 7, d = i & 127;
            const float* g = Gm + m * 512;
            float gi = g[d], go = g[128 + d], gu = g[256 + d], gf = g[384 + d];
            float cc = C[(size_t)left[s10 + bm0 + m] * 128 + d];
            float c = sigf(gi) * tanhf(gu) + sigf(gf) * cc;
            float h = sigf(go) * tanhf(c);
            out[((size_t)(bm0 + m) * 1024 + 1023) * 128 + d] = h;
        }
    }
}

extern "C" void kernel_launch(void* const* d_in, const int* in_sizes, int n_in,
                              void* d_out, int out_size, void* d_ws, size_t ws_size,
                              hipStream_t stream) {
    const int*   tokens = (const int*)d_in[0];
    const int*   left   = (const int*)d_in[1];
    const int*   right  = (const int*)d_in[2];
    const float* emb    = (const float*)d_in[3];
    const float* W_un   = (const float*)d_in[4];
    const float* b_un   = (const float*)d_in[5];
    const float* W_bin  = (const float*)d_in[6];
    const float* b_bin  = (const float*)d_in[7];
    float* out = (float*)d_out;

    unsigned short* Hhi  = (unsigned short*)d_ws;
    float*          C    = (float*)((char*)d_ws + 33554432);
    unsigned short* Wext = (unsigned short*)((char*)d_ws + 67108864);
    unsigned int*   bar  = (unsigned int*)((char*)d_ws + 71303168);   // 68 MB

    init_bar<<<1, 64, 0, stream>>>(bar);
    fused<<<NB, 256, 0, stream>>>(tokens, left, right, emb, W_un, b_un,
                                  W_bin, b_bin, out, Hhi, C, Wext, bar);
}

// Round 13
// 368.062 us; speedup vs baseline: 1.8554x; 1.8554x over previous
//
#include <hip/hip_runtime.h>
#include <math.h>

// TreeLSTM encoder v5 (hybrid): per-level dispatches for levels 1-2,
// one 128-block persistent tail kernel for levels 3-10 (software grid barrier),
// prep_w folded into leaf dispatch. K-loop/epilogue identical to passing v3.
// ws layout (bytes):
//   [0,16M)    Hhi plane: [65536][128] bf16
//   [16M,32M)  Hlo plane: [65536][128] bf16
//   [32M,64M)  C plane:   [65536][128] f32
//   [64M,+640K) W_ext:    [640 cols][512] bf16 (k<256 hi, k>=256 lo)
//   [68M,+64B) barrier counters (16 x u32), zeroed by init kernel each call
// K_ext = 768: term0 Xh*Wh, term1 Xh*Wl, term2 Xl*Wh.

typedef __attribute__((ext_vector_type(8))) short s8_t;
typedef __attribute__((ext_vector_type(4))) float f32x4;

#define PLANE_DELTA 8388608   // ushorts between Hhi and Hlo planes
#define NBT 128               // tail kernel grid: 128 blocks, trivially co-resident

__device__ __forceinline__ float sigf(float x){ return 1.0f/(1.0f+expf(-x)); }

__device__ __forceinline__ unsigned short f2bf_rne(float x){
    unsigned int u = __builtin_bit_cast(unsigned int, x);
    unsigned int r = (u + 0x7FFFu + ((u>>16)&1u)) >> 16;
    return (unsigned short)r;
}
__device__ __forceinline__ float bf2f(unsigned short b){
    return __builtin_bit_cast(float, ((unsigned int)b)<<16);
}
__device__ __forceinline__ void gl_lds16(const void* g, void* l){
    __builtin_amdgcn_global_load_lds(
        (const __attribute__((address_space(1))) unsigned int*)g,
        (__attribute__((address_space(3))) unsigned int*)l, 16, 0, 0);
}

__device__ __forceinline__ void gridbar(unsigned int* cnt, unsigned nb) {
    __syncthreads();
    if (threadIdx.x == 0) {
        __hip_atomic_fetch_add(cnt, 1u, __ATOMIC_RELEASE, __HIP_MEMORY_SCOPE_AGENT);
        while (__hip_atomic_load(cnt, __ATOMIC_RELAXED, __HIP_MEMORY_SCOPE_AGENT) < nb)
            __builtin_amdgcn_s_sleep(8);
        __threadfence();
    }
    __syncthreads();
}

__global__ void init_bar(unsigned int* bar) {
    if (threadIdx.x < 16) bar[threadIdx.x] = 0;
}

// ---------------- Level 0: leaves + W prep (folded) ----------------
__global__ __launch_bounds__(256) void leaf_kernel(
    const int* __restrict__ tokens, const float* __restrict__ emb,
    const float* __restrict__ Wb, unsigned short* __restrict__ Wext,
    unsigned short* __restrict__ Hhi, float* __restrict__ C,
    float* __restrict__ out, int n_leaves)
{
    // W prep: blocks 0..639 convert one element/thread
    int widx = blockIdx.x * 256 + threadIdx.x;
    if (widx < 640 * 256) {
        int nn = widx >> 8, k = widx & 255;
        float x = Wb[k * 640 + nn];
        unsigned short h = f2bf_rne(x);
        Wext[nn * 512 + k]       = h;
        Wext[nn * 512 + 256 + k] = f2bf_rne(x - bf2f(h));
    }

    int node = blockIdx.x * 4 + (threadIdx.x >> 6);
    if (node >= n_leaves) return;
    int lane = threadIdx.x & 63;
    int tok = tokens[node];
    float2 e = *(const float2*)(emb + (size_t)tok * 128 + lane * 2);
    float ss = e.x * e.x + e.y * e.y;
#pragma unroll
    for (int off = 32; off; off >>= 1) ss += __shfl_xor(ss, off, 64);
    float nrm = sqrtf(ss);
    float scale = fminf(1.0f, 1.0f / fmaxf(nrm, 1e-7f));
    float hx = e.x * scale, hy = e.y * scale;
    unsigned short hxh = f2bf_rne(hx), hyh = f2bf_rne(hy);
    unsigned short hxl = f2bf_rne(hx - bf2f(hxh)), hyl = f2bf_rne(hy - bf2f(hyh));
    size_t p = (size_t)node * 128 + lane * 2;
    *(unsigned int*)(Hhi + p)               = (unsigned int)hxh | ((unsigned int)hyh << 16);
    *(unsigned int*)(Hhi + p + PLANE_DELTA) = (unsigned int)hxl | ((unsigned int)hyl << 16);
    *(float2*)(C + p) = make_float2(0.f, 0.f);
    int t = node >> 9, j = node & 511;
    *(float2*)(out + ((size_t)t * 1024 + j) * 128 + lane * 2) = make_float2(hx, hy);
}

// ---------------- shared body: one 128x160 tile of a binary level ----------------
__device__ __forceinline__ void bin_tile(
    unsigned short* __restrict__ Hhi, float* __restrict__ C,
    const int* __restrict__ left, const int* __restrict__ right,
    const unsigned short* __restrict__ Wext, const float* __restrict__ bb,
    float* __restrict__ out,
    int s, int n_nodes, int out_off, int log2c, int bm0, int d0,
    unsigned short* SL, unsigned short* dmy, int* sLR)
{
    const int tid  = threadIdx.x;
    const int lane = tid & 63;
    const int w    = tid >> 6;

    if (tid < 128) {
        int r = bm0 + tid; if (r >= n_nodes) r = n_nodes - 1;
        sLR[tid]       = left[s + r];
        sLR[128 + tid] = right[s + r];
    }
    __syncthreads();

    int aOffL[2], aOffR[2];
#pragma unroll
    for (int j = 0; j < 2; ++j) {
        int ch = tid + j * 256, row = ch >> 2, slot = ch & 3;
        int g = slot ^ ((row >> 1) & 3);
        aOffL[j] = sLR[row] * 256 + g * 16;
        aOffR[j] = sLR[128 + row] * 256 + g * 16;
    }
    int bOff0, bOff1, bOff2;
    {
        int nn = tid >> 2, slot = tid & 3;
        int g = slot ^ ((nn >> 1) & 3);
        bOff0 = ((nn >> 5) * 128 + d0 + (nn & 31)) * 1024 + g * 16;
    }
    {
        int ch = tid + 256, nn = ch >> 2, slot = ch & 3;
        int g = slot ^ ((nn >> 1) & 3);
        bOff1 = ((nn >> 5) * 128 + d0 + (nn & 31)) * 1024 + g * 16;
    }
    if (tid < 128) {
        int ch = tid + 512, nn = ch >> 2, slot = ch & 3;
        int g = slot ^ ((nn >> 1) & 3);
        bOff2 = ((nn >> 5) * 128 + d0 + (nn & 31)) * 1024 + g * 16;
    } else {
        bOff2 = 0;
    }

    const char* HhiB  = (const char*)Hhi;
    const char* WextB = (const char*)Wext;

    f32x4 acc[2][10];
#pragma unroll
    for (int i = 0; i < 2; ++i)
#pragma unroll
        for (int j = 0; j < 10; ++j) acc[i][j] = f32x4{0.f, 0.f, 0.f, 0.f};

    auto stage = [&](int st, int buf) {
        const int tm    = st >> 3;
        const int k256  = (st & 7) * 32;
        const int side  = k256 >> 7;
        const int aoffB = ((tm == 2) ? PLANE_DELTA * 2 : 0) + (k256 & 127) * 2;
        const int koffB = ((tm == 1) ? (256 + k256) : k256) * 2;
        char* Abase = (char*)SL + buf * 18432;
        char* Bbase = Abase + 8192;
        const int a0 = side ? aOffR[0] : aOffL[0];
        const int a1 = side ? aOffR[1] : aOffL[1];
        gl_lds16(HhiB + (size_t)(a0 + aoffB), Abase + w * 1024);
        gl_lds16(HhiB + (size_t)(a1 + aoffB), Abase + 4096 + w * 1024);
        gl_lds16(WextB + (size_t)(bOff0 + koffB), Bbase + w * 1024);
        gl_lds16(WextB + (size_t)(bOff1 + koffB), Bbase + 4096 + w * 1024);
        gl_lds16(WextB + (size_t)(bOff2 + koffB),
                 (w < 2) ? (void*)(Bbase + 8192 + w * 1024)
                         : (void*)((char*)dmy + (w - 2) * 1024));
    };

    const int r15  = lane & 15;
    const int sl_  = (lane >> 4) ^ ((r15 >> 1) & 3);
    const int offA = w * 2048 + r15 * 64 + sl_ * 16;
    const int offB = r15 * 64 + sl_ * 16;

    stage(0, 0);
    stage(1, 1);
    stage(2, 2);
    int cbuf = 0, sbuf = 3;
#pragma unroll 1
    for (int st = 0; st < 24; ++st) {
        if (st <= 21)      asm volatile("s_waitcnt vmcnt(10)" ::: "memory");
        else if (st == 22) asm volatile("s_waitcnt vmcnt(5)"  ::: "memory");
        else               asm volatile("s_waitcnt vmcnt(0)"  ::: "memory");
        __builtin_amdgcn_sched_barrier(0);
        __builtin_amdgcn_s_barrier();
        __builtin_amdgcn_sched_barrier(0);
        if (st + 3 < 24) stage(st + 3, sbuf);
        const char* Ap = (const char*)SL + cbuf * 18432;
        const char* Bp = Ap + 8192;
        s8_t a0v = *(const s8_t*)(Ap + offA);
        s8_t a1v = *(const s8_t*)(Ap + offA + 1024);
#pragma unroll
        for (int fn = 0; fn < 10; ++fn) {
            s8_t bf = *(const s8_t*)(Bp + offB + fn * 1024);
            acc[0][fn] = __builtin_amdgcn_mfma_f32_16x16x32_bf16(a0v, bf, acc[0][fn], 0, 0, 0);
            acc[1][fn] = __builtin_amdgcn_mfma_f32_16x16x32_bf16(a1v, bf, acc[1][fn], 0, 0, 0);
        }
        cbuf = (cbuf == 3) ? 0 : cbuf + 1;
        sbuf = (sbuf == 3) ? 0 : sbuf + 1;
    }

    float bias[5][2];
#pragma unroll
    for (int g = 0; g < 5; ++g) {
        bias[g][0] = bb[g * 128 + d0 + r15];
        bias[g][1] = bb[g * 128 + d0 + 16 + r15];
    }
#pragma unroll
    for (int fm = 0; fm < 2; ++fm) {
        const int rb = w * 32 + fm * 16 + ((lane >> 4) << 2);
#pragma unroll
        for (int reg = 0; reg < 4; ++reg) {
            const int rl = rb + reg;
            const int nl = bm0 + rl;
            const bool valid = nl < n_nodes;
            const int node = s + (valid ? nl : 0);
            const int ln = sLR[rl], rn = sLR[128 + rl];
#pragma unroll
            for (int hi = 0; hi < 2; ++hi) {
                const int d = d0 + hi * 16 + r15;
                float gi  = acc[fm][0 + hi][reg] + bias[0][hi];
                float go  = acc[fm][2 + hi][reg] + bias[1][hi];
                float gu  = acc[fm][4 + hi][reg] + bias[2][hi];
                float gfl = acc[fm][6 + hi][reg] + bias[3][hi];
                float gfr = acc[fm][8 + hi][reg] + bias[4][hi];
                float lc = C[(size_t)ln * 128 + d];
                float rc = C[(size_t)rn * 128 + d];
                float c = sigf(gi) * tanhf(gu) + sigf(gfl) * lc + sigf(gfr) * rc;
                float h = sigf(go) * tanhf(c);
                if (valid) {
                    size_t p = (size_t)node * 128 + d;
                    unsigned short hh = f2bf_rne(h);
                    Hhi[p]               = hh;
                    Hhi[p + PLANE_DELTA] = f2bf_rne(h - bf2f(hh));
                    C[p] = c;
                    const int tt = nl >> log2c, j = nl & ((1 << log2c) - 1);
                    out[((size_t)tt * 1024 + out_off + j) * 128 + d] = h;
                }
            }
        }
    }
}

// ---------------- Levels 1-2: standalone dispatch ----------------
__global__ __launch_bounds__(256, 2) void bin3(
    unsigned short* __restrict__ Hhi, float* __restrict__ C,
    const int* __restrict__ left, const int* __restrict__ right,
    const unsigned short* __restrict__ Wext, const float* __restrict__ bb,
    float* __restrict__ out, int s, int n_nodes, int out_off, int log2c)
{
    __shared__ __align__(16) unsigned short SL[4 * 9216];
    __shared__ __align__(16) unsigned short dmy[1024];
    __shared__ int sLR[256];
    bin_tile(Hhi, C, left, right, Wext, bb, out, s, n_nodes, out_off, log2c,
             blockIdx.x * 128, blockIdx.y * 32, SL, dmy, sLR);
}

// ---------------- Levels 3-10: persistent tail (128 blocks) ----------------
__global__ __launch_bounds__(256, 2) void tail(
    unsigned short* __restrict__ Hhi, float* __restrict__ C,
    const int* __restrict__ left, const int* __restrict__ right,
    const unsigned short* __restrict__ Wext, const float* __restrict__ bb,
    const float* __restrict__ Wu, const float* __restrict__ bu,
    float* __restrict__ out, unsigned int* __restrict__ bar)
{
    __shared__ __align__(16) unsigned short SL[4 * 9216];
    __shared__ __align__(16) unsigned short dmy[1024];
    __shared__ int sLR[256];

    const int b = blockIdx.x, tid = threadIdx.x;

#pragma unroll 1
    for (int l = 3; l <= 9; ++l) {
        const int n_nodes = 32768 >> l;
        const int s       = 65536 - (65536 >> l);
        const int ooff    = 1024 - (1024 >> l);
        const int lg      = 9 - l;
        const int Tx      = (n_nodes + 127) >> 7;
        const int active  = Tx * 4;

        if (b < active) {
            int t = b;
            if (active >= 8) { int q = active >> 3; t = (b & 7) * q + (b >> 3); }
            bin_tile(Hhi, C, left, right, Wext, bb, out, s, n_nodes, ooff, lg,
                     (t >> 2) * 128, (t & 3) * 32, SL, dmy, sLR);
        }
        gridbar(&bar[l], NBT);
    }

    // level 10: unary head on blocks 0..3
    if (b < 4) {
        float* X = (float*)SL;
        const int bm0 = b * 16;
        const int s10 = 65472;
        for (int i = tid; i < 16 * 128; i += 256) {
            int m = i >> 7, d = i & 127;
            int ch = left[s10 + bm0 + m];
            size_t p = (size_t)ch * 128 + d;
            X[m * 128 + d] = bf2f(Hhi[p]) + bf2f(Hhi[p + PLANE_DELTA]);
        }
        __syncthreads();

        float acc0[16], acc1[16];
#pragma unroll
        for (int m = 0; m < 16; ++m) { acc0[m] = 0.f; acc1[m] = 0.f; }

        for (int k4 = 0; k4 < 32; ++k4) {
            const int k = k4 * 4;
            float w0[4], w1[4];
#pragma unroll
            for (int r = 0; r < 4; ++r) {
                w0[r] = Wu[(k + r) * 512 + tid];
                w1[r] = Wu[(k + r) * 512 + tid + 256];
            }
#pragma unroll
            for (int m = 0; m < 16; ++m) {
                float4 xv = *(const float4*)(X + m * 128 + k);
                acc0[m] = fmaf(xv.x, w0[0], fmaf(xv.y, w0[1], fmaf(xv.z, w0[2], fmaf(xv.w, w0[3], acc0[m]))));
                acc1[m] = fmaf(xv.x, w1[0], fmaf(xv.y, w1[1], fmaf(xv.z, w1[2], fmaf(xv.w, w1[3], acc1[m]))));
            }
        }

        float b0 = bu[tid], b1 = bu[tid + 256];
        __syncthreads();
        float* Gm = (float*)SL;
#pragma unroll
        for (int m = 0; m < 16; ++m) {
            Gm[m * 512 + tid]       = acc0[m] + b0;
            Gm[m * 512 + tid + 256] = acc1[m] + b1;
        }
        __syncthreads();

        for (int i = tid; i < 16 * 128; i += 256) {
            int m = i >> 7, d = i & 127;
            const float* g = Gm + m * 512;
            float gi = g[d], go = g[128 + d], gu = g[256 + d], gf = g[384 + d];
            float cc = C[(size_t)left[s10 + bm0 + m] * 128 + d];
            float c = sigf(gi) * tanhf(gu) + sigf(gf) * cc;
            float h = sigf(go) * tanhf(c);
            out[((size_t)(bm0 + m) * 1024 + 1023) * 128 + d] = h;
        }
    }
}

extern "C" void kernel_launch(void* const* d_in, const int* in_sizes, int n_in,
                              void* d_out, int out_size, void* d_ws, size_t ws_size,
                              hipStream_t stream) {
    const int*   tokens = (const int*)d_in[0];
    const int*   left   = (const int*)d_in[1];
    const int*   right  = (const int*)d_in[2];
    const float* emb    = (const float*)d_in[3];
    const float* W_un   = (const float*)d_in[4];
    const float* b_un   = (const float*)d_in[5];
    const float* W_bin  = (const float*)d_in[6];
    const float* b_bin  = (const float*)d_in[7];
    float* out = (float*)d_out;

    unsigned short* Hhi  = (unsigned short*)d_ws;
    float*          C    = (float*)((char*)d_ws + 33554432);
    unsigned short* Wext = (unsigned short*)((char*)d_ws + 67108864);
    unsigned int*   bar  = (unsigned int*)((char*)d_ws + 71303168);

    init_bar<<<1, 64, 0, stream>>>(bar);
    leaf_kernel<<<8192, 256, 0, stream>>>(tokens, emb, W_bin, Wext, Hhi, C, out, 32768);

    // levels 1-2 as dispatches (big grids benefit from full-device redistribution)
    bin3<<<dim3(128, 4), 256, 0, stream>>>(Hhi, C, left, right, Wext, b_bin,
                                           out, 32768, 16384, 512, 8);
    bin3<<<dim3(64, 4), 256, 0, stream>>>(Hhi, C, left, right, Wext, b_bin,
                                          out, 49152, 8192, 768, 7);

    // levels 3-10 fused
    tail<<<NBT, 256, 0, stream>>>(Hhi, C, left, right, Wext, b_bin,
                                  W_un, b_un, out, bar);
}